// Round 1
// baseline (389.904 us; speedup 1.0000x reference)
//
#include <hip/hip_runtime.h>

// ---------------------------------------------------------------------------
// PairEdgeLearnGNN on MI355X.
// B=64, N=1024, D=128, KT=13, NC=2, CF=2.
//   scores = x (w1 w2^T) x^T ; adj = softmax over axis=1 (columns)
//   h = (adj + I) x ; g = h gin_w^T + gin_b ; BN1 per-n over (b,d)
//   z[b,c,d] = sum_n bn1(g) lc_w[c,n] ; conv K=13 SAME ; BN2 ; relu ; linear ; softmax
// Outputs: probs (64x2) then adj (64x1024x1024), f32, concatenated.
// ---------------------------------------------------------------------------

typedef __attribute__((ext_vector_type(8))) short bf16x8;
typedef __attribute__((ext_vector_type(4))) float f32x4;

__device__ __forceinline__ float b2f(unsigned short s){
  union { unsigned u; float f; } v; v.u = ((unsigned)s) << 16; return v.f;
}
__device__ __forceinline__ unsigned short f2b(float f){
  union { float f; unsigned u; } v; v.f = f;
  unsigned r = v.u + 0x7fffu + ((v.u >> 16) & 1u);
  return (unsigned short)(r >> 16);
}

#define MFMA16(a, b, c) __builtin_amdgcn_mfma_f32_16x16x32_bf16((a), (b), (c), 0, 0, 0)

// ---------------------------------------------------------------------------
// prep: blk<8192: 32x32 transpose tiles -> xb (bf16) + xbT (bf16)
//       blk in [8192,8256): cast gin_w -> bf16
//       blk in [8256,8320): Mt[d][k] = sum_e w1[k,e] w2[d,e]  (= (w1 w2^T)^T)
// ---------------------------------------------------------------------------
__global__ __launch_bounds__(256) void k_prep(
    const float* __restrict__ x, const float* __restrict__ w1, const float* __restrict__ w2,
    const float* __restrict__ gin_w,
    unsigned short* __restrict__ xb, unsigned short* __restrict__ xbT,
    unsigned short* __restrict__ mt, unsigned short* __restrict__ ginb)
{
  int blk = blockIdx.x, tid = threadIdx.x;
  if (blk < 8192) {
    __shared__ float tile[32][33];
    int b = blk >> 7, t = blk & 127;
    int j0 = (t >> 2) << 5, d0 = (t & 3) << 5;
    int tx = tid & 31, ty = tid >> 5;
#pragma unroll
    for (int r0 = 0; r0 < 32; r0 += 8) {
      int r = ty + r0;
      int idx = (((b << 10) + j0 + r) << 7) + d0 + tx;
      float v = x[idx];
      tile[r][tx] = v;
      xb[idx] = f2b(v);
    }
    __syncthreads();
#pragma unroll
    for (int r0 = 0; r0 < 32; r0 += 8) {
      int r = ty + r0;
      xbT[(((b << 7) + d0 + r) << 10) + j0 + tx] = f2b(tile[tx][r]);
    }
  } else if (blk < 8256) {
    int i = ((blk - 8192) << 8) + tid;
    ginb[i] = f2b(gin_w[i]);
  } else {
    int i = ((blk - 8256) << 8) + tid;   // 0..16383
    int d = i >> 7, k = i & 127;
    float s = 0.f;
    for (int e = 0; e < 128; ++e) s += w1[(k << 7) + e] * w2[(d << 7) + e];
    mt[(d << 7) + k] = f2b(s);
  }
}

// ---------------------------------------------------------------------------
// NT GEMM, M x 128, K=128: Out[row,col] = sum_k A[row,k] Bt[col,k] (+ bias[col])
// tile 128 rows/block, direct-from-global fragments, bf16 MFMA, bf16 out.
// ---------------------------------------------------------------------------
__global__ __launch_bounds__(256, 2) void k_gemm_nt128(
    const unsigned short* __restrict__ A, const unsigned short* __restrict__ Bt,
    const float* __restrict__ bias, unsigned short* __restrict__ Out)
{
  int row0 = blockIdx.x << 7;
  int tid = threadIdx.x;
  int wave = tid >> 6, lane = tid & 63, lr = lane & 15, lg = lane >> 4;
  f32x4 acc[2][8] = {};
#pragma unroll
  for (int kk = 0; kk < 4; kk++) {
    bf16x8 a[2], bb[8];
#pragma unroll
    for (int fi = 0; fi < 2; fi++)
      a[fi] = *(const bf16x8*)&A[((size_t)(row0 + (wave << 5) + (fi << 4) + lr) << 7) + (kk << 5) + (lg << 3)];
#pragma unroll
    for (int cf = 0; cf < 8; cf++)
      bb[cf] = *(const bf16x8*)&Bt[(((cf << 4) + lr) << 7) + (kk << 5) + (lg << 3)];
#pragma unroll
    for (int fi = 0; fi < 2; fi++)
#pragma unroll
      for (int cf = 0; cf < 8; cf++)
        acc[fi][cf] = MFMA16(a[fi], bb[cf], acc[fi][cf]);
  }
#pragma unroll
  for (int fi = 0; fi < 2; fi++) {
#pragma unroll
    for (int cf = 0; cf < 8; cf++) {
      int col = (cf << 4) + lr;
      float bv = bias ? bias[col] : 0.f;
      int rowb = row0 + (wave << 5) + (fi << 4) + (lg << 2);
#pragma unroll
      for (int r = 0; r < 4; r++)
        Out[((size_t)(rowb + r) << 7) + col] = f2b(acc[fi][cf][r] + bv);
    }
  }
}

// ---------------------------------------------------------------------------
// colsum pass: per (b, i-tile, j-tile) compute 128x128 score tile, exp, and
// write deterministic per-i-tile partial column sums psum[it][b*1024+j].
// ---------------------------------------------------------------------------
__global__ __launch_bounds__(256, 2) void k_colsum(
    const unsigned short* __restrict__ qb, const unsigned short* __restrict__ xb,
    float* __restrict__ psum)
{
  int blk = blockIdx.x;
  int b = blk >> 6, rr = blk & 63, it = rr >> 3, jt = rr & 7;
  int tid = threadIdx.x, wave = tid >> 6, lane = tid & 63, lr = lane & 15, lg = lane >> 4;
  const unsigned short* Ab = qb + ((size_t)(b << 10) << 7);
  const unsigned short* Bb = xb + ((size_t)(b << 10) << 7);
  f32x4 s[2][8] = {};
#pragma unroll
  for (int kk = 0; kk < 4; kk++) {
    bf16x8 a[2], bb[8];
#pragma unroll
    for (int fi = 0; fi < 2; fi++)
      a[fi] = *(const bf16x8*)&Ab[((size_t)((it << 7) + (wave << 5) + (fi << 4) + lr) << 7) + (kk << 5) + (lg << 3)];
#pragma unroll
    for (int cf = 0; cf < 8; cf++)
      bb[cf] = *(const bf16x8*)&Bb[((size_t)((jt << 7) + (cf << 4) + lr) << 7) + (kk << 5) + (lg << 3)];
#pragma unroll
    for (int fi = 0; fi < 2; fi++)
#pragma unroll
      for (int cf = 0; cf < 8; cf++)
        s[fi][cf] = MFMA16(a[fi], bb[cf], s[fi][cf]);
  }
  __shared__ float lw[4][128];
  float ps[8];
#pragma unroll
  for (int cf = 0; cf < 8; cf++) {
    float p = 0.f;
#pragma unroll
    for (int fi = 0; fi < 2; fi++)
#pragma unroll
      for (int r = 0; r < 4; r++) p += __expf(s[fi][cf][r]);
    p += __shfl_xor(p, 16);
    p += __shfl_xor(p, 32);
    ps[cf] = p;
  }
  if (lane < 16) {
#pragma unroll
    for (int cf = 0; cf < 8; cf++) lw[wave][(cf << 4) + lane] = ps[cf];
  }
  __syncthreads();
  if (tid < 128) {
    float tot = lw[0][tid] + lw[1][tid] + lw[2][tid] + lw[3][tid];
    psum[(size_t)it * 65536 + (b << 10) + (jt << 7) + tid] = tot;
  }
}

__global__ void k_rcol(const float* __restrict__ psum, float* __restrict__ rcol)
{
  int i = (blockIdx.x << 8) + threadIdx.x;
  float s = 0.f;
#pragma unroll
  for (int it = 0; it < 8; it++) s += psum[(size_t)it * 65536 + i];
  rcol[i] = 1.f / s;
}

// ---------------------------------------------------------------------------
// fused: recompute scores, P = exp(s)*rcol[j], write adj (f32), and
// accumulate h = P @ x  (+ x added in epilogue), hb out bf16.
// P transposed D-layout -> A-layout via per-wave-private swizzled LDS tile.
// ---------------------------------------------------------------------------
__global__ __launch_bounds__(256, 2) void k_attn(
    const unsigned short* __restrict__ qb, const unsigned short* __restrict__ xb,
    const unsigned short* __restrict__ xbT, const float* __restrict__ rcol,
    float* __restrict__ adj, unsigned short* __restrict__ hb)
{
  int blk = blockIdx.x;
  int b = blk >> 3, it = blk & 7;
  int i0 = it << 7;
  int tid = threadIdx.x, wave = tid >> 6, lane = tid & 63, lr = lane & 15, lg = lane >> 4;
  __shared__ unsigned short plds[4][32][128];   // per-wave private 32x128, XOR-swizzled
  __shared__ float rc[128];
  const unsigned short* Ab = qb + ((size_t)(b << 10) << 7);
  const unsigned short* Xb = xb + ((size_t)(b << 10) << 7);
  const unsigned short* Xt = xbT + ((size_t)(b << 7) << 10);
  f32x4 h[2][8] = {};

  for (int jt = 0; jt < 8; jt++) {
    int j0 = jt << 7;
    __syncthreads();
    if (tid < 128) rc[tid] = rcol[(b << 10) + j0 + tid];
    __syncthreads();

    // scores tile
    f32x4 s[2][8] = {};
#pragma unroll
    for (int kk = 0; kk < 4; kk++) {
      bf16x8 a[2], bb[8];
#pragma unroll
      for (int fi = 0; fi < 2; fi++)
        a[fi] = *(const bf16x8*)&Ab[((size_t)(i0 + (wave << 5) + (fi << 4) + lr) << 7) + (kk << 5) + (lg << 3)];
#pragma unroll
      for (int cf = 0; cf < 8; cf++)
        bb[cf] = *(const bf16x8*)&Xb[((size_t)(j0 + (cf << 4) + lr) << 7) + (kk << 5) + (lg << 3)];
#pragma unroll
      for (int fi = 0; fi < 2; fi++)
#pragma unroll
        for (int cf = 0; cf < 8; cf++)
          s[fi][cf] = MFMA16(a[fi], bb[cf], s[fi][cf]);
    }

    // exp * rcol -> adj write + swizzled LDS (bf16) for PV A-operand
#pragma unroll
    for (int fi = 0; fi < 2; fi++) {
#pragma unroll
      for (int cf = 0; cf < 8; cf++) {
        int colj = (cf << 4) + lr;
        float rv = rc[colj];
#pragma unroll
        for (int r = 0; r < 4; r++) {
          int lrow = (fi << 4) + (lg << 2) + r;       // 0..31 within wave strip
          float p = __expf(s[fi][cf][r]) * rv;
          int irow = i0 + (wave << 5) + lrow;
          adj[((size_t)((b << 10) + irow) << 10) + j0 + colj] = p;
          int sw = (colj >> 3) ^ (lrow & 7);
          plds[wave][lrow][(sw << 3) | (colj & 7)] = f2b(p);
        }
      }
    }
    __syncthreads();

    // PV: h += P @ x   (B from xbT, contiguous fragments)
#pragma unroll
    for (int kk = 0; kk < 4; kk++) {
      bf16x8 pa[2], vb[8];
#pragma unroll
      for (int fi = 0; fi < 2; fi++) {
        int lrow = (fi << 4) + lr;
        int jb = ((kk << 2) + lg) ^ (lrow & 7);
        pa[fi] = *(const bf16x8*)&plds[wave][lrow][jb << 3];
      }
#pragma unroll
      for (int cf = 0; cf < 8; cf++)
        vb[cf] = *(const bf16x8*)&Xt[((size_t)((cf << 4) + lr) << 10) + j0 + (kk << 5) + (lg << 3)];
#pragma unroll
      for (int fi = 0; fi < 2; fi++)
#pragma unroll
        for (int cf = 0; cf < 8; cf++)
          h[fi][cf] = MFMA16(pa[fi], vb[cf], h[fi][cf]);
    }
  }

  // epilogue: h += x ; store bf16
#pragma unroll
  for (int fi = 0; fi < 2; fi++) {
#pragma unroll
    for (int cf = 0; cf < 8; cf++) {
      int col = (cf << 4) + lr;
      int rowb = i0 + (wave << 5) + (fi << 4) + (lg << 2);
#pragma unroll
      for (int r = 0; r < 4; r++) {
        int row = rowb + r;
        float v = h[fi][cf][r] + b2f(Xb[((size_t)row << 7) + col]);
        hb[((size_t)((b << 10) + row) << 7) + col] = f2b(v);
      }
    }
  }
}

// ---------------------------------------------------------------------------
// BN1 stats per n over (b,d): fold into w'[c,n] = lc_w*r*gamma and
// bterm[c,n] = lc_w*(beta - m*r*gamma)  (+ lc_b at n==0).
// ---------------------------------------------------------------------------
__global__ __launch_bounds__(256) void k_bnstats(
    const unsigned short* __restrict__ gb, const float* __restrict__ lc_w,
    const float* __restrict__ lc_b, const float* __restrict__ bn1_g,
    const float* __restrict__ bn1_b, float* __restrict__ wprime, float* __restrict__ bterm)
{
  int n = blockIdx.x, tid = threadIdx.x;
  float s = 0.f, s2 = 0.f;
  for (int i = tid; i < 8192; i += 256) {
    int b = i >> 7, d = i & 127;
    float v = b2f(gb[((size_t)((b << 10) + n) << 7) + d]);
    s += v; s2 += v * v;
  }
  __shared__ float rs[256], rs2[256];
  rs[tid] = s; rs2[tid] = s2;
  __syncthreads();
  for (int o = 128; o > 0; o >>= 1) {
    if (tid < o) { rs[tid] += rs[tid + o]; rs2[tid] += rs2[tid + o]; }
    __syncthreads();
  }
  if (tid == 0) {
    float m = rs[0] * (1.f / 8192.f);
    float var = rs2[0] * (1.f / 8192.f) - m * m;
    float r = rsqrtf(var + 1e-5f);
    float rg = r * bn1_g[n];
    float t = bn1_b[n] - m * rg;
#pragma unroll
    for (int c = 0; c < 2; c++) {
      float w = lc_w[(c << 10) + n];
      wprime[(c << 10) + n] = w * rg;
      float bt = w * t;
      if (n == 0) bt += lc_b[c];
      bterm[(c << 10) + n] = bt;
    }
  }
}

// z partials: zp[nc][(b*2+c)*128+d] = sum over n-chunk of g*w'
__global__ __launch_bounds__(128) void k_zred(
    const unsigned short* __restrict__ gb, const float* __restrict__ wprime,
    float* __restrict__ zp)
{
  int blk = blockIdx.x;
  int b = blk >> 3, nc = blk & 7, n0 = nc << 7, d = threadIdx.x;
  float a0 = 0.f, a1 = 0.f;
  for (int n = n0; n < n0 + 128; ++n) {
    float w0 = wprime[n], w1v = wprime[1024 + n];
    float g = b2f(gb[((size_t)((b << 10) + n) << 7) + d]);
    a0 += g * w0; a1 += g * w1v;
  }
  zp[(size_t)nc * 16384 + ((b << 1) << 7) + d] = a0;
  zp[(size_t)nc * 16384 + (((b << 1) | 1) << 7) + d] = a1;
}

// ---------------------------------------------------------------------------
// final single block: z = sum(zp)+bias' ; conv K=13 SAME ; BN2 over (b,d) ;
// relu ; logits ; softmax -> probs.
// ---------------------------------------------------------------------------
__global__ __launch_bounds__(1024) void k_final(
    const float* __restrict__ zp, const float* __restrict__ bterm,
    const float* __restrict__ conv_w, const float* __restrict__ conv_b,
    const float* __restrict__ bn2_g, const float* __restrict__ bn2_b,
    const float* __restrict__ out_w, const float* __restrict__ out_b,
    float* __restrict__ probs)
{
  __shared__ float smem[16384];   // reused: red -> zs -> red/u
  __shared__ float bp[2], ms[2];
  __shared__ float cw[26];
  int tid = threadIdx.x;
  if (tid < 26) cw[tid] = conv_w[tid];

  // bias' = lc_b + sum_n bterm   (lc_b folded into bterm[n==0])
  for (int c = 0; c < 2; c++) {
    smem[tid] = bterm[(c << 10) + tid];
    __syncthreads();
    for (int o = 512; o > 0; o >>= 1) {
      if (tid < o) smem[tid] += smem[tid + o];
      __syncthreads();
    }
    if (tid == 0) bp[c] = smem[0];
    __syncthreads();
  }

  // z
  for (int i = tid; i < 16384; i += 1024) {
    float s = 0.f;
#pragma unroll
    for (int p = 0; p < 8; p++) s += zp[(size_t)p * 16384 + i];
    smem[i] = s + bp[(i >> 7) & 1];
  }
  __syncthreads();

  // conv + bn2 partial stats (8 outputs per thread)
  float o[8];
  float s = 0.f, s2 = 0.f;
#pragma unroll
  for (int k = 0; k < 8; k++) {
    int i = tid + (k << 10);
    int b = i >> 7, d = i & 127;
    float acc = conv_b[0];
#pragma unroll
    for (int c = 0; c < 2; c++) {
      const float* zrow = &smem[((b << 1) | c) << 7];
#pragma unroll
      for (int t = 0; t < 13; t++) {
        int dd = d + t - 6;
        if (dd >= 0 && dd < 128) acc += zrow[dd] * cw[c * 13 + t];
      }
    }
    o[k] = acc; s += acc; s2 += acc * acc;
  }
  __syncthreads();          // all conv reads of smem done
  smem[tid] = s; smem[1024 + tid] = s2;
  __syncthreads();
  for (int off = 512; off > 0; off >>= 1) {
    if (tid < off) { smem[tid] += smem[tid + off]; smem[1024 + tid] += smem[1024 + tid + off]; }
    __syncthreads();
  }
  if (tid == 0) {
    float m = smem[0] * (1.f / 8192.f);
    float var = smem[1024] * (1.f / 8192.f) - m * m;
    ms[0] = m; ms[1] = rsqrtf(var + 1e-5f);
  }
  __syncthreads();
  float m = ms[0], r = ms[1], g2 = bn2_g[0], b2v = bn2_b[0];
#pragma unroll
  for (int k = 0; k < 8; k++) {
    int i = tid + (k << 10);
    smem[i & 8191] = fmaxf(0.f, (o[k] - m) * r * g2 + b2v);   // u[b*128+d], i<8192 always hits k<8
  }
  __syncthreads();

  // logits + softmax (16 threads per b)
  int b = tid >> 4, q = tid & 15;
  float l0 = 0.f, l1 = 0.f;
#pragma unroll
  for (int k = 0; k < 8; k++) {
    int d = q + (k << 4);
    float uv = smem[(b << 7) + d];
    l0 += uv * out_w[d];
    l1 += uv * out_w[128 + d];
  }
#pragma unroll
  for (int off = 8; off > 0; off >>= 1) { l0 += __shfl_xor(l0, off); l1 += __shfl_xor(l1, off); }
  if (q == 0) {
    l0 += out_b[0]; l1 += out_b[1];
    float mm = fmaxf(l0, l1);
    float e0 = __expf(l0 - mm), e1 = __expf(l1 - mm);
    float inv = 1.f / (e0 + e1);
    probs[(b << 1)] = e0 * inv;
    probs[(b << 1) | 1] = e1 * inv;
  }
}

// ---------------------------------------------------------------------------
extern "C" void kernel_launch(void* const* d_in, const int* in_sizes, int n_in,
                              void* d_out, int out_size, void* d_ws, size_t ws_size,
                              hipStream_t stream)
{
  const float* x      = (const float*)d_in[0];
  const float* w1     = (const float*)d_in[1];
  const float* w2     = (const float*)d_in[2];
  const float* gin_w  = (const float*)d_in[3];
  const float* gin_b  = (const float*)d_in[4];
  const float* bn1_g  = (const float*)d_in[5];
  const float* bn1_b  = (const float*)d_in[6];
  const float* lc_w   = (const float*)d_in[7];
  const float* lc_b   = (const float*)d_in[8];
  const float* conv_w = (const float*)d_in[9];
  const float* conv_b = (const float*)d_in[10];
  const float* bn2_g  = (const float*)d_in[11];
  const float* bn2_b  = (const float*)d_in[12];
  const float* out_w  = (const float*)d_in[13];
  const float* out_b  = (const float*)d_in[14];

  char* ws = (char*)d_ws;
  unsigned short* xb   = (unsigned short*)(ws);                                  // 16 MiB
  unsigned short* xbT  = (unsigned short*)(ws + ((size_t)16 << 20));             // 16 MiB
  unsigned short* qb   = (unsigned short*)(ws + ((size_t)32 << 20));             // 16 MiB
  unsigned short* hb   = (unsigned short*)(ws + ((size_t)48 << 20));             // 16 MiB
  unsigned short* mt   = (unsigned short*)(ws + ((size_t)64 << 20));             // 32 KiB
  unsigned short* ginb = (unsigned short*)(ws + ((size_t)64 << 20) + (32u << 10));
  float* psum   = (float*)(ws + ((size_t)64 << 20) + (64u << 10));               // 2 MiB
  float* rcolp  = (float*)(ws + ((size_t)66 << 20) + (64u << 10));               // 256 KiB
  float* wprime = (float*)(ws + ((size_t)66 << 20) + (320u << 10));              // 8 KiB
  float* bterm  = (float*)(ws + ((size_t)66 << 20) + (328u << 10));              // 8 KiB
  float* zp     = (float*)(ws + ((size_t)66 << 20) + (336u << 10));              // 512 KiB
  unsigned short* gb = xb;   // alias: xb dead after k_attn

  float* probs = (float*)d_out;
  float* adj   = probs + 128;

  k_prep<<<8320, 256, 0, stream>>>(x, w1, w2, gin_w, xb, xbT, mt, ginb);
  k_gemm_nt128<<<512, 256, 0, stream>>>(xb, mt, nullptr, qb);          // q = x (w1 w2^T)
  k_colsum<<<4096, 256, 0, stream>>>(qb, xb, psum);
  k_rcol<<<256, 256, 0, stream>>>(psum, rcolp);
  k_attn<<<512, 256, 0, stream>>>(qb, xb, xbT, rcolp, adj, hb);        // adj + h=(adj+I)x
  k_gemm_nt128<<<512, 256, 0, stream>>>(hb, ginb, gin_b, gb);          // g = h gin_w^T + b
  k_bnstats<<<1024, 256, 0, stream>>>(gb, lc_w, lc_b, bn1_g, bn1_b, wprime, bterm);
  k_zred<<<512, 128, 0, stream>>>(gb, wprime, zp);
  k_final<<<1, 1024, 0, stream>>>(zp, bterm, conv_w, conv_b, bn2_g, bn2_b, out_w, out_b, probs);
}